// Round 5
// baseline (148.313 us; speedup 1.0000x reference)
//
#include <hip/hip_runtime.h>
#include <math.h>

#define DIM 512
#define HID 8
#define LN_EPS 1e-5f

typedef float f32x4 __attribute__((ext_vector_type(4)));

// ---- DPP cross-lane helpers (VALU-speed, no LDS) ----
#define DPP_XOR1 0xB1   // quad_perm [1,0,3,2] : xor1
#define DPP_XOR2 0x4E   // quad_perm [2,3,0,1] : xor2
#define DPP_HM   0x141  // row_half_mirror (i^7 in 8): ==xor4 once 4-uniform
#define DPP_ROR8 0x128  // (i+8)&15 == i^8 : xor8 within 16

template <int CTRL>
__device__ __forceinline__ float dpp_movf(float v) {
    int r = __builtin_amdgcn_update_dpp(0, __builtin_bit_cast(int, v),
                                        CTRL, 0xF, 0xF, true);
    return __builtin_bit_cast(float, r);
}
template <int CTRL>
__device__ __forceinline__ float dpp_addf(float v) {
    return v + dpp_movf<CTRL>(v);
}
__device__ __forceinline__ float readlanef(float v, int lane) {
    return __builtin_bit_cast(float,
        __builtin_amdgcn_readlane(__builtin_bit_cast(int, v), lane));
}

// tanh-GELU via hardware exp2/rcp (abs err ~1e-3 vs exact; threshold 0.166)
__device__ __forceinline__ float gelu_fast(float v) {
    const float C = 0.044715f;
    const float K = 2.30258819f; // 2*0.7978845608*log2(e)
    float v2 = v * v;
    float t  = v * fmaf(C, v2, 1.0f);
    float e  = __builtin_amdgcn_exp2f(K * t);
    float r  = __builtin_amdgcn_rcpf(e + 1.0f);
    return fmaf(-v, r, v);
}

// in-wave reduce of 8 partials; returns wave-complete sum of partial[lane&7]
__device__ __forceinline__ float reduce8(float ph[8], int lj) {
#pragma unroll
    for (int j = 0; j < 8; ++j) ph[j] = dpp_addf<DPP_XOR1>(ph[j]);
#pragma unroll
    for (int j = 0; j < 8; ++j) ph[j] = dpp_addf<DPP_XOR2>(ph[j]);
#pragma unroll
    for (int j = 0; j < 8; ++j) ph[j] = dpp_addf<DPP_HM>(ph[j]);
    float sel = ph[0];
    sel = (lj == 1) ? ph[1] : sel;
    sel = (lj == 2) ? ph[2] : sel;
    sel = (lj == 3) ? ph[3] : sel;
    sel = (lj == 4) ? ph[4] : sel;
    sel = (lj == 5) ? ph[5] : sel;
    sel = (lj == 6) ? ph[6] : sel;
    sel = (lj == 7) ? ph[7] : sel;
    sel = dpp_addf<DPP_ROR8>(sel);
    sel += __shfl_xor(sel, 16, 64);
    sel += __shfl_xor(sel, 32, 64);
    return sel;
}

// full wave sum of a scalar (DPP tree + 4 readlanes)
__device__ __forceinline__ float wave_sum(float v) {
    v = dpp_addf<DPP_XOR1>(v);
    v = dpp_addf<DPP_XOR2>(v);
    v = dpp_addf<DPP_HM>(v);
    v = dpp_addf<DPP_ROR8>(v);
    return (readlanef(v, 0) + readlanef(v, 16))
         + (readlanef(v, 32) + readlanef(v, 48));
}

__global__ __launch_bounds__(128, 4)
void mlp_fused_kernel(const float* __restrict__ x,
                      const float* __restrict__ w1,
                      const float* __restrict__ b1,
                      const float* __restrict__ w2,
                      const float* __restrict__ b2,
                      const float* __restrict__ gamma,
                      const float* __restrict__ beta,
                      float* __restrict__ out,
                      int nrows, int rows_per_block) {
    __shared__ float lds[96];   // [0..63]: 2 row-buffers; [64..95]: startup

    const int tid  = threadIdx.x;
    const int lane = tid & 63;
    const int w    = tid >> 6;            // wave 0/1: owns d half
    const int lj   = lane & 7;
    const int dbase = w * 256 + lane * 4; // 4 consecutive d's per lane

    const int r0 = blockIdx.x * rows_per_block;
    if (r0 >= nrows) return;
    int r1 = r0 + rows_per_block;
    if (r1 > nrows) r1 = nrows;

    // ---- startup: hoist + fold weights ----
    f32x4 gmv = *reinterpret_cast<const f32x4*>(gamma + dbase);
    f32x4 btv = *reinterpret_cast<const f32x4*>(beta  + dbase);

    float w1g[32];                        // w1g[j*4+k] = w1[j, dbase+k]*gamma
    float c1p[8], w1sp[8];
#pragma unroll
    for (int j = 0; j < 8; ++j) { c1p[j] = 0.f; w1sp[j] = 0.f; }
#pragma unroll
    for (int j = 0; j < 8; ++j) {
        f32x4 raw = *reinterpret_cast<const f32x4*>(w1 + j * DIM + dbase);
#pragma unroll
        for (int k = 0; k < 4; ++k) {
            float rw = raw[k];
            c1p[j] = fmaf(btv[k], rw, c1p[j]);
            float wg = rw * gmv[k];
            w1g[j * 4 + k] = wg;
            w1sp[j] += wg;
        }
    }
    float w1sw = reduce8(w1sp, lj);       // wave-partial Sum_d w1g[j,d]
    float c1w  = reduce8(c1p, lj);        // wave-partial Sum_d beta_d*w1[j,d]
    if (lane < 8) {
        lds[64 + w * 8 + lj] = w1sw;
        lds[80 + w * 8 + lj] = c1w;
    }
    __syncthreads();
    const float W1s = lds[64 + lj] + lds[72 + lj];
    const float b1e = b1[lj] + lds[80 + lj] + lds[88 + lj];

    float w2n[32];                        // w2n[k*8+j] = w2[dbase+k, j]
#pragma unroll
    for (int k = 0; k < 4; ++k) {
        f32x4 lo = *reinterpret_cast<const f32x4*>(w2 + (size_t)(dbase + k) * HID);
        f32x4 hi = *reinterpret_cast<const f32x4*>(w2 + (size_t)(dbase + k) * HID + 4);
#pragma unroll
        for (int j = 0; j < 4; ++j) { w2n[k * 8 + j] = lo[j]; w2n[k * 8 + 4 + j] = hi[j]; }
    }
    f32x4 b2v = *reinterpret_cast<const f32x4*>(b2 + dbase);

    // ---- prefetch first row ----
    f32x4 xv = *reinterpret_cast<const f32x4*>(x + (size_t)r0 * DIM + dbase);

    for (int r = r0; r < r1; ++r) {
        // prefetch next row (clamped)
        const int rn = (r + 1 < r1) ? (r + 1) : r;
        f32x4 xn = *reinterpret_cast<const f32x4*>(x + (size_t)rn * DIM + dbase);

        // ---- local partials (depend only on xv) ----
        float s = 0.f, q = 0.f;
#pragma unroll
        for (int k = 0; k < 4; ++k) { s += xv[k]; q = fmaf(xv[k], xv[k], q); }

        float ph[8];
#pragma unroll
        for (int j = 0; j < 8; ++j) {
            float a = 0.f;
#pragma unroll
            for (int k = 0; k < 4; ++k)
                a = fmaf(xv[k], w1g[j * 4 + k], a);
            ph[j] = a;
        }

        // ---- single merged in-wave reduction phase ----
        const float sw = wave_sum(s);
        const float qw = wave_sum(q);
        const float Hw = reduce8(ph, lj);   // wave-partial Sum_d x_d*w1g[j,d]

        // ---- one LDS round-trip per row (double-buffered by parity) ----
        const int base = (r & 1) * 32;
        if (lane == 0) {
            lds[base + w * 2 + 0] = sw;
            lds[base + w * 2 + 1] = qw;
        }
        if (lane < 8) lds[base + 4 + w * 8 + lj] = Hw;
        __syncthreads();

        const float stot = lds[base + 0] + lds[base + 2];
        const float qtot = lds[base + 1] + lds[base + 3];
        const float Sx   = lds[base + 4 + lj] + lds[base + 12 + lj];

        const float mu  = stot * (1.0f / DIM);
        const float var = qtot * (1.0f / DIM) - mu * mu;
        const float rs  = rsqrtf(var + LN_EPS);

        // h[lj] = rs*(Sx - mu*W1s) + b1e ; one gelu per lane
        const float t  = fmaf(-mu, W1s, Sx);
        const float vH = gelu_fast(fmaf(rs, t, b1e));

        // H[0..7] -> SGPRs
        float sH[8];
#pragma unroll
        for (int j = 0; j < 8; ++j) sH[j] = readlanef(vH, j);

        // ---- stage 2: o[d] = gelu(sum_j H[j]*w2[d,j] + b2[d]) + x[d] ----
        f32x4 ov;
#pragma unroll
        for (int k = 0; k < 4; ++k) {
            float o = b2v[k];
#pragma unroll
            for (int j = 0; j < 8; ++j)
                o = fmaf(sH[j], w2n[k * 8 + j], o);
            ov[k] = gelu_fast(o) + xv[k];
        }

        // ---- one coalesced nontemporal dwordx4 store per lane ----
        __builtin_nontemporal_store(
            ov, reinterpret_cast<f32x4*>(out + (size_t)r * DIM + dbase));

        xv = xn;
    }
}

extern "C" void kernel_launch(void* const* d_in, const int* in_sizes, int n_in,
                              void* d_out, int out_size, void* d_ws, size_t ws_size,
                              hipStream_t stream) {
    const float* x     = (const float*)d_in[0];
    const float* w1    = (const float*)d_in[1];
    const float* b1    = (const float*)d_in[2];
    const float* w2    = (const float*)d_in[3];
    const float* b2    = (const float*)d_in[4];
    const float* gamma = (const float*)d_in[5];
    const float* beta  = (const float*)d_in[6];
    float* out = (float*)d_out;

    const int nrows  = in_sizes[0] / DIM;     // 131072
    const int blocks = 4096;                  // 2 waves (1 row-slice pair) each
    const int rows_per_block = (nrows + blocks - 1) / blocks;  // 32

    mlp_fused_kernel<<<blocks, 128, 0, stream>>>(
        x, w1, b1, w2, b2, gamma, beta, out, nrows, rows_per_block);
}

// Round 6
// 126.894 us; speedup vs baseline: 1.1688x; 1.1688x over previous
//
#include <hip/hip_runtime.h>
#include <math.h>

#define DIM 512
#define HID 8
#define LN_EPS 1e-5f

typedef float f32x4 __attribute__((ext_vector_type(4)));

// ---- DPP cross-lane helpers (VALU-speed, no LDS) ----
#define DPP_XOR1 0xB1   // quad_perm [1,0,3,2] : xor1
#define DPP_XOR2 0x4E   // quad_perm [2,3,0,1] : xor2
#define DPP_HM   0x141  // row_half_mirror (i^7 within 8): ==xor4 once 4-uniform
#define DPP_ROR8 0x128  // (i+8)&15 == i^8 : xor8 within 16
#define DPP_ROR4 0x124  // (i+4)&15 : ==xor4 (mod 8) on 8-periodic data

template <int CTRL>
__device__ __forceinline__ float dpp_movf(float v) {
    int r = __builtin_amdgcn_update_dpp(0, __builtin_bit_cast(int, v),
                                        CTRL, 0xF, 0xF, true);
    return __builtin_bit_cast(float, r);
}
template <int CTRL>
__device__ __forceinline__ float dpp_addf(float v) {
    return v + dpp_movf<CTRL>(v);
}
__device__ __forceinline__ float readlanef(float v, int lane) {
    return __builtin_bit_cast(float,
        __builtin_amdgcn_readlane(__builtin_bit_cast(int, v), lane));
}

// tanh-GELU via hardware exp2/rcp (abs err ~1e-3 vs exact; threshold 0.166)
__device__ __forceinline__ float gelu_fast(float v) {
    const float C = 0.044715f;
    const float K = 2.30258819f; // 2*0.7978845608*log2(e)
    float v2 = v * v;
    float t  = v * fmaf(C, v2, 1.0f);
    float e  = __builtin_amdgcn_exp2f(K * t);
    float r  = __builtin_amdgcn_rcpf(e + 1.0f);
    return fmaf(-v, r, v);
}

// full wave sum of a scalar (4 DPP adds + 4 readlanes + 3 adds)
__device__ __forceinline__ float wave_sum(float v) {
    v = dpp_addf<DPP_XOR1>(v);
    v = dpp_addf<DPP_XOR2>(v);
    v = dpp_addf<DPP_HM>(v);
    v = dpp_addf<DPP_ROR8>(v);
    return (readlanef(v, 0) + readlanef(v, 16))
         + (readlanef(v, 32) + readlanef(v, 48));
}

// reduce 8 partials; every lane ends with wave-complete sum of partial[lane&7]
__device__ __forceinline__ float reduce8(float ph[8], int lj) {
#pragma unroll
    for (int j = 0; j < 8; ++j) ph[j] = dpp_addf<DPP_XOR1>(ph[j]);
#pragma unroll
    for (int j = 0; j < 8; ++j) ph[j] = dpp_addf<DPP_XOR2>(ph[j]);
#pragma unroll
    for (int j = 0; j < 8; ++j) ph[j] = dpp_addf<DPP_HM>(ph[j]);
    float sel = ph[0];
    sel = (lj == 1) ? ph[1] : sel;
    sel = (lj == 2) ? ph[2] : sel;
    sel = (lj == 3) ? ph[3] : sel;
    sel = (lj == 4) ? ph[4] : sel;
    sel = (lj == 5) ? ph[5] : sel;
    sel = (lj == 6) ? ph[6] : sel;
    sel = (lj == 7) ? ph[7] : sel;
    sel = dpp_addf<DPP_ROR8>(sel);
    sel += __shfl_xor(sel, 16, 64);
    sel += __shfl_xor(sel, 32, 64);
    return sel;
}

__device__ __forceinline__ void load8(float* dst, const float* __restrict__ src) {
    const f32x4* p = reinterpret_cast<const f32x4*>(src);
    f32x4 a = p[0];
    f32x4 b = p[1];
    dst[0] = a.x; dst[1] = a.y; dst[2] = a.z; dst[3] = a.w;
    dst[4] = b.x; dst[5] = b.y; dst[6] = b.z; dst[7] = b.w;
}

// waves_per_eu(2,2): clamp MAX occupancy so the register allocator has no
// incentive to remat/reload the ~130 row-invariant weight values — the whole
// working set (~200 VGPR) stays resident. No asm pins (R4's pins cost ~150
// pseudo-ops/row).
__global__ __launch_bounds__(256)
__attribute__((amdgpu_waves_per_eu(2, 2)))
void mlp_fused_kernel(const float* __restrict__ x,
                      const float* __restrict__ w1,
                      const float* __restrict__ b1,
                      const float* __restrict__ w2,
                      const float* __restrict__ b2,
                      const float* __restrict__ gamma,
                      const float* __restrict__ beta,
                      float* __restrict__ out,
                      int nrows, int rows_per_wave) {
    const int lane  = threadIdx.x & 63;
    const int wav   = threadIdx.x >> 6;
    const int wgid  = blockIdx.x * 4 + wav;
    const int dbase = lane * 8;
    const int lj    = lane & 7;

    const int r0 = wgid * rows_per_wave;
    if (r0 >= nrows) return;
    int r1 = r0 + rows_per_wave;
    if (r1 > nrows) r1 = nrows;

    // ---- startup: load + fold weights (gamma/beta die after this) ----
    float gm[8], bt[8];
    load8(gm, gamma + dbase);
    load8(bt, beta  + dbase);

    float w1g[64];                 // w1g[j*8+k] = w1[j, dbase+k] * gamma[dbase+k]
    float w1sp[8], c1p[8];
#pragma unroll
    for (int j = 0; j < 8; ++j) { w1sp[j] = 0.f; c1p[j] = 0.f; }
#pragma unroll
    for (int j = 0; j < 8; ++j) {
        float raw[8];
        load8(raw, w1 + j * DIM + dbase);
#pragma unroll
        for (int k = 0; k < 8; ++k) {
            c1p[j] = fmaf(bt[k], raw[k], c1p[j]);
            float wg = raw[k] * gm[k];
            w1g[j * 8 + k] = wg;
            w1sp[j] += wg;
        }
    }
    const float W1s = reduce8(w1sp, lj);          // Sum_d w1g[lj, d]
    const float b1e = b1[lj] + reduce8(c1p, lj);  // b1 + Sum_d beta_d*w1[lj,d]

    float w2p[64];                 // w2p[k*8+t] = w2[dbase+k, lj^t]
#pragma unroll
    for (int k = 0; k < 8; ++k)
#pragma unroll
        for (int t = 0; t < 8; ++t)
            w2p[k * 8 + t] = w2[(size_t)(dbase + k) * HID + (lj ^ t)];

    float b2r[8];
    load8(b2r, b2 + dbase);

    // ---- prefetch first row pair ----
    float xvA[8], xvB[8];
    load8(xvA, x + (size_t)r0 * DIM + dbase);
    {
        int rb = (r0 + 1 < r1) ? r0 + 1 : r0;
        load8(xvB, x + (size_t)rb * DIM + dbase);
    }

    int r = r0;
    for (; r + 1 < r1; r += 2) {
        // prefetch next pair (clamped)
        float xnA[8], xnB[8];
        const int ra2 = (r + 2 < r1) ? r + 2 : r1 - 1;
        const int rb2 = (r + 3 < r1) ? r + 3 : r1 - 1;
        load8(xnA, x + (size_t)ra2 * DIM + dbase);
        load8(xnB, x + (size_t)rb2 * DIM + dbase);

        // ---- local partials for both rows (independent chains) ----
        float sA = 0.f, qA = 0.f, sB = 0.f, qB = 0.f;
#pragma unroll
        for (int k = 0; k < 8; ++k) {
            sA += xvA[k]; qA = fmaf(xvA[k], xvA[k], qA);
            sB += xvB[k]; qB = fmaf(xvB[k], xvB[k], qB);
        }
        float phA[8], phB[8];
#pragma unroll
        for (int j = 0; j < 8; ++j) {
            float a = 0.f, b = 0.f;
#pragma unroll
            for (int k = 0; k < 8; ++k) {
                a = fmaf(xvA[k], w1g[j * 8 + k], a);
                b = fmaf(xvB[k], w1g[j * 8 + k], b);
            }
            phA[j] = a; phB[j] = b;
        }

        // ---- reductions (6 independent trees interleave) ----
        const float swA = wave_sum(sA);
        const float qwA = wave_sum(qA);
        const float swB = wave_sum(sB);
        const float qwB = wave_sum(qB);
        const float HwA = reduce8(phA, lj);
        const float HwB = reduce8(phB, lj);

        // ---- row A epilogue ----
        const float muA  = swA * (1.0f / DIM);
        const float varA = qwA * (1.0f / DIM) - muA * muA;
        const float rsA  = rsqrtf(varA + LN_EPS);
        const float hA   = gelu_fast(fmaf(rsA, fmaf(-muA, W1s, HwA), b1e));
        float hjA[8];
        hjA[0] = hA;
        hjA[1] = dpp_movf<DPP_XOR1>(hjA[0]);
        hjA[2] = dpp_movf<DPP_XOR2>(hjA[0]);
        hjA[3] = dpp_movf<DPP_XOR2>(hjA[1]);
        hjA[4] = dpp_movf<DPP_ROR4>(hjA[0]);
        hjA[5] = dpp_movf<DPP_ROR4>(hjA[1]);
        hjA[6] = dpp_movf<DPP_ROR4>(hjA[2]);
        hjA[7] = dpp_movf<DPP_ROR4>(hjA[3]);
        f32x4 oA0, oA1;
#pragma unroll
        for (int k = 0; k < 8; ++k) {
            float o = b2r[k];
#pragma unroll
            for (int t = 0; t < 8; ++t)
                o = fmaf(hjA[t], w2p[k * 8 + t], o);
            float val = gelu_fast(o) + xvA[k];
            if (k < 4) oA0[k] = val; else oA1[k - 4] = val;
        }
        {
            float* po = out + (size_t)r * DIM + dbase;
            __builtin_nontemporal_store(oA0, reinterpret_cast<f32x4*>(po));
            __builtin_nontemporal_store(oA1, reinterpret_cast<f32x4*>(po) + 1);
        }

        // ---- row B epilogue ----
        const float muB  = swB * (1.0f / DIM);
        const float varB = qwB * (1.0f / DIM) - muB * muB;
        const float rsB  = rsqrtf(varB + LN_EPS);
        const float hB   = gelu_fast(fmaf(rsB, fmaf(-muB, W1s, HwB), b1e));
        float hjB[8];
        hjB[0] = hB;
        hjB[1] = dpp_movf<DPP_XOR1>(hjB[0]);
        hjB[2] = dpp_movf<DPP_XOR2>(hjB[0]);
        hjB[3] = dpp_movf<DPP_XOR2>(hjB[1]);
        hjB[4] = dpp_movf<DPP_ROR4>(hjB[0]);
        hjB[5] = dpp_movf<DPP_ROR4>(hjB[1]);
        hjB[6] = dpp_movf<DPP_ROR4>(hjB[2]);
        hjB[7] = dpp_movf<DPP_ROR4>(hjB[3]);
        f32x4 oB0, oB1;
#pragma unroll
        for (int k = 0; k < 8; ++k) {
            float o = b2r[k];
#pragma unroll
            for (int t = 0; t < 8; ++t)
                o = fmaf(hjB[t], w2p[k * 8 + t], o);
            float val = gelu_fast(o) + xvB[k];
            if (k < 4) oB0[k] = val; else oB1[k - 4] = val;
        }
        {
            float* po = out + (size_t)(r + 1) * DIM + dbase;
            __builtin_nontemporal_store(oB0, reinterpret_cast<f32x4*>(po));
            __builtin_nontemporal_store(oB1, reinterpret_cast<f32x4*>(po) + 1);
        }

#pragma unroll
        for (int k = 0; k < 8; ++k) { xvA[k] = xnA[k]; xvB[k] = xnB[k]; }
    }

    // ---- odd tail row ----
    if (r < r1) {
        float s = 0.f, q = 0.f;
#pragma unroll
        for (int k = 0; k < 8; ++k) { s += xvA[k]; q = fmaf(xvA[k], xvA[k], q); }
        float ph[8];
#pragma unroll
        for (int j = 0; j < 8; ++j) {
            float a = 0.f;
#pragma unroll
            for (int k = 0; k < 8; ++k)
                a = fmaf(xvA[k], w1g[j * 8 + k], a);
            ph[j] = a;
        }
        const float sw = wave_sum(s);
        const float qw = wave_sum(q);
        const float Hw = reduce8(ph, lj);
        const float mu  = sw * (1.0f / DIM);
        const float var = qw * (1.0f / DIM) - mu * mu;
        const float rs  = rsqrtf(var + LN_EPS);
        const float h   = gelu_fast(fmaf(rs, fmaf(-mu, W1s, Hw), b1e));
        float hj[8];
        hj[0] = h;
        hj[1] = dpp_movf<DPP_XOR1>(hj[0]);
        hj[2] = dpp_movf<DPP_XOR2>(hj[0]);
        hj[3] = dpp_movf<DPP_XOR2>(hj[1]);
        hj[4] = dpp_movf<DPP_ROR4>(hj[0]);
        hj[5] = dpp_movf<DPP_ROR4>(hj[1]);
        hj[6] = dpp_movf<DPP_ROR4>(hj[2]);
        hj[7] = dpp_movf<DPP_ROR4>(hj[3]);
        f32x4 o0, o1;
#pragma unroll
        for (int k = 0; k < 8; ++k) {
            float o = b2r[k];
#pragma unroll
            for (int t = 0; t < 8; ++t)
                o = fmaf(hj[t], w2p[k * 8 + t], o);
            float val = gelu_fast(o) + xvA[k];
            if (k < 4) o0[k] = val; else o1[k - 4] = val;
        }
        float* po = out + (size_t)r * DIM + dbase;
        __builtin_nontemporal_store(o0, reinterpret_cast<f32x4*>(po));
        __builtin_nontemporal_store(o1, reinterpret_cast<f32x4*>(po) + 1);
    }
}

extern "C" void kernel_launch(void* const* d_in, const int* in_sizes, int n_in,
                              void* d_out, int out_size, void* d_ws, size_t ws_size,
                              hipStream_t stream) {
    const float* x     = (const float*)d_in[0];
    const float* w1    = (const float*)d_in[1];
    const float* b1    = (const float*)d_in[2];
    const float* w2    = (const float*)d_in[3];
    const float* b2    = (const float*)d_in[4];
    const float* gamma = (const float*)d_in[5];
    const float* beta  = (const float*)d_in[6];
    float* out = (float*)d_out;

    const int nrows  = in_sizes[0] / DIM;         // 131072
    const int blocks = 512;                       // 4 waves each = 2048 waves
    const int total_waves = blocks * 4;           // ~exactly resident @2/SIMD
    const int rows_per_wave = (nrows + total_waves - 1) / total_waves;  // 64

    mlp_fused_kernel<<<blocks, 256, 0, stream>>>(
        x, w1, b1, w2, b2, gamma, beta, out, nrows, rows_per_wave);
}